// Round 19
// baseline (246.420 us; speedup 1.0000x reference)
//
#include <hip/hip_runtime.h>
#include <math.h>

// Problem constants (B=2, T=2048, C=2048, HQ=16, HKV=4, Dh=128, WIN=256)
#define BB   2
#define TT   2048
#define CC   2048
#define HQ_  16
#define HKV_ 4
#define DH   128
#define MM   (BB * TT)          // 4096 rows
#define KVC  (HKV_ * DH)        // 512
#define QVN  (CC + KVC)         // 2560: fused Q|V projection width

typedef __attribute__((ext_vector_type(8)))  _Float16 f16x8;
typedef __attribute__((ext_vector_type(4)))  float    f32x4;
typedef __attribute__((ext_vector_type(16))) float    f32x16;

__device__ __forceinline__ unsigned short f2h(float x) {
    _Float16 h = (_Float16)x;                 // RNE v_cvt_f16_f32
    return __builtin_bit_cast(unsigned short, h);
}
__device__ __forceinline__ float h2f(unsigned short u) {
    return (float)__builtin_bit_cast(_Float16, u);
}
__device__ __forceinline__ unsigned pk2(float a, float b) {
    return (unsigned)f2h(a) | ((unsigned)f2h(b) << 16);
}
__device__ __forceinline__ unsigned pkrtz(float a, float b) {
    typedef __attribute__((ext_vector_type(2))) __fp16 fp16v2;   // builtin's native type
    const fp16v2 h = __builtin_amdgcn_cvt_pkrtz(a, b);           // 1 instr, RTZ
    return __builtin_bit_cast(unsigned, h);
}
__device__ __forceinline__ void gll16(const void* g, void* l) {
    __builtin_amdgcn_global_load_lds(
        (const __attribute__((address_space(1))) unsigned int*)g,
        (__attribute__((address_space(3))) unsigned int*)l, 16, 0, 0);
}
// bijective XCD-aware tile remap (T1, m204 form).
__device__ __forceinline__ int xcd_swizzle(int lid, int nwg) {
    const int xcd = lid & 7, rank = lid >> 3;
    const int q8 = nwg >> 3, r8 = nwg & 7;
    return (xcd < r8 ? xcd * (q8 + 1) : r8 * (q8 + 1) + (xcd - r8) * q8) + rank;
}

// ---------------------------------------------------------------------------
// prep: ONE dispatch = fp32->fp16 cast of x (+) transpose-casts of Wq,Wv,Wo.
// ---------------------------------------------------------------------------
__device__ __forceinline__ void tcast_tile(const float* __restrict__ W,
                                           unsigned short* __restrict__ WT,
                                           int Kd, int Nd, int n0, int k0,
                                           float Ls[32][33]) {
    const int i = threadIdx.x;
    {
        const int kr = i >> 3, n4 = (i & 7) * 4;
        float4 v = *(const float4*)&W[(size_t)(k0 + kr) * Nd + n0 + n4];
        Ls[kr][n4 + 0] = v.x; Ls[kr][n4 + 1] = v.y;
        Ls[kr][n4 + 2] = v.z; Ls[kr][n4 + 3] = v.w;
    }
    __syncthreads();
    {
        const int nr = i >> 3, k4 = (i & 7) * 4;
        uint2 o;
        o.x = pk2(Ls[k4 + 0][nr], Ls[k4 + 1][nr]);
        o.y = pk2(Ls[k4 + 2][nr], Ls[k4 + 3][nr]);
        *(uint2*)&WT[(size_t)(n0 + nr) * Kd + k0 + k4] = o;
    }
}

__global__ __launch_bounds__(256)
void prep(const float* __restrict__ x,  unsigned short* __restrict__ xb,
          const float* __restrict__ Wq, const float* __restrict__ Wv,
          const float* __restrict__ Wo, unsigned short* __restrict__ WqvT,
          unsigned short* __restrict__ WoT) {
    __shared__ float Ls[32][33];
    const int bid = blockIdx.x;
    if (bid < 2048) {
        const int n8 = MM * CC / 8;
        int i = bid * 256 + threadIdx.x;
        for (; i < n8; i += 2048 * 256) {
            const float4 a = ((const float4*)x)[i * 2 + 0];
            const float4 b = ((const float4*)x)[i * 2 + 1];
            uint4 o;
            o.x = pk2(a.x, a.y); o.y = pk2(a.z, a.w);
            o.z = pk2(b.x, b.y); o.w = pk2(b.z, b.w);
            ((uint4*)xb)[i] = o;
        }
    } else if (bid < 2048 + 4096) {
        const int t = bid - 2048;
        tcast_tile(Wq, WqvT, CC, CC, (t & 63) * 32, (t >> 6) * 32, Ls);
    } else if (bid < 2048 + 4096 + 1024) {
        const int t = bid - (2048 + 4096);
        tcast_tile(Wv, WqvT + (size_t)CC * CC, CC, KVC, (t & 15) * 32, (t >> 4) * 32, Ls);
    } else {
        const int t = bid - (2048 + 4096 + 1024);
        tcast_tile(Wo, WoT, CC, CC, (t & 63) * 32, (t >> 6) * 32, Ls);
    }
}

// ---------------------------------------------------------------------------
// fp16 MFMA GEMM, B^T input (m97 structure + T1 swizzle). Unchanged.
// ---------------------------------------------------------------------------
template<int F16OUT>
__global__ __launch_bounds__(256)
void gemm_bt(const unsigned short* __restrict__ A, const unsigned short* __restrict__ Bt,
             void* __restrict__ Cout, int M, int N, int K) {
    __shared__ __align__(16) unsigned short As[128 * 64];
    __shared__ __align__(16) unsigned short Bs[128 * 64];
    const int tid  = threadIdx.x;
    const int lane = tid & 63, wid = tid >> 6;
    const int g = lane >> 4, l15 = lane & 15;
    const int nwg  = gridDim.x * gridDim.y;
    const int tile = xcd_swizzle(blockIdx.y * gridDim.x + blockIdx.x, nwg);
    const int bm = (tile / gridDim.x) * 128, bn = (tile % gridDim.x) * 128;
    const int wr = (wid >> 1) * 64, wc = (wid & 1) * 64;

    f32x4 acc[4][4] = {};

    for (int kt = 0; kt < K; kt += 64) {
        __syncthreads();
#pragma unroll
        for (int r = 0; r < 4; ++r) {
            const int q = r * 256 + tid;
            const int row = q >> 3, c = q & 7, sc = c ^ (row & 7);
            gll16(A + (size_t)(bm + row) * K + kt + sc * 8, As + q * 8);
        }
#pragma unroll
        for (int r = 0; r < 4; ++r) {
            const int q = r * 256 + tid;
            const int row = q >> 3, c = q & 7, sc = c ^ (row & 7);
            gll16(Bt + (size_t)(bn + row) * K + kt + sc * 8, Bs + q * 8);
        }
        __syncthreads();

#pragma unroll
        for (int kk = 0; kk < 2; ++kk) {
            f16x8 af[4], bfr[4];
#pragma unroll
            for (int m = 0; m < 4; ++m) {
                const int row = wr + m * 16 + l15;
                const int ch = (kk * 4 + g) ^ (row & 7);
                af[m] = *(const f16x8*)&As[row * 64 + ch * 8];
            }
#pragma unroll
            for (int n = 0; n < 4; ++n) {
                const int row = wc + n * 16 + l15;
                const int ch = (kk * 4 + g) ^ (row & 7);
                bfr[n] = *(const f16x8*)&Bs[row * 64 + ch * 8];
            }
#pragma unroll
            for (int m = 0; m < 4; ++m)
#pragma unroll
                for (int n = 0; n < 4; ++n)
                    acc[m][n] = __builtin_amdgcn_mfma_f32_16x16x32_f16(
                        af[m], bfr[n], acc[m][n], 0, 0, 0);
        }
    }

#pragma unroll
    for (int m = 0; m < 4; ++m)
#pragma unroll
        for (int n = 0; n < 4; ++n)
#pragma unroll
            for (int r = 0; r < 4; ++r) {
                const int row = bm + wr + m * 16 + g * 4 + r;
                const int col = bn + wc + n * 16 + l15;
                const float v = acc[m][n][r];
                if (F16OUT)
                    ((unsigned short*)Cout)[(size_t)row * N + col] = f2h(v);
                else
                    ((float*)Cout)[(size_t)row * N + col] = v;
            }
}

// ---------------------------------------------------------------------------
// kvprep: fused K=rmsnorm(V) + Vt transpose build. Unchanged.
// ---------------------------------------------------------------------------
__global__ __launch_bounds__(256)
void kvprep(const unsigned short* __restrict__ Vg,
            unsigned short* __restrict__ Kb, unsigned short* __restrict__ Vt) {
    __shared__ unsigned short Ls[32][132];
    const int t0 = blockIdx.x * 32;
    const int bh = blockIdx.y;
    const int b = bh >> 2, hk = bh & 3;
    const int tid = threadIdx.x;

    const int tr = tid >> 3, c16 = (tid & 7) * 16;
    const unsigned short* src =
        Vg + (size_t)(b * TT + t0 + tr) * QVN + hk * DH + c16;
    const uint4 u0 = *(const uint4*)(src);
    const uint4 u1 = *(const uint4*)(src + 8);
    *(uint4*)&Ls[tr][c16]     = u0;
    *(uint4*)&Ls[tr][c16 + 8] = u1;

    float v[16];
    {
        const unsigned uu[8] = {u0.x, u0.y, u0.z, u0.w, u1.x, u1.y, u1.z, u1.w};
#pragma unroll
        for (int j = 0; j < 8; ++j) {
            v[2 * j]     = h2f((unsigned short)(uu[j] & 0xffff));
            v[2 * j + 1] = h2f((unsigned short)(uu[j] >> 16));
        }
    }
    float ss = 0.f;
#pragma unroll
    for (int j = 0; j < 16; ++j) ss += v[j] * v[j];
    ss += __shfl_xor(ss, 1);
    ss += __shfl_xor(ss, 2);
    ss += __shfl_xor(ss, 4);
    const float sc = rsqrtf(ss * (1.f / DH) + 1.1920929e-07f);

    {
        unsigned short* kd = Kb + (size_t)(b * TT + t0 + tr) * KVC + hk * DH + c16;
        unsigned oo[8];
#pragma unroll
        for (int j = 0; j < 8; ++j)
            oo[j] = pk2(v[2 * j] * sc, v[2 * j + 1] * sc);
        *(uint4*)(kd)     = make_uint4(oo[0], oo[1], oo[2], oo[3]);
        *(uint4*)(kd + 8) = make_uint4(oo[4], oo[5], oo[6], oo[7]);
    }
    __syncthreads();

    {
        const int dr = tid >> 1, t16 = (tid & 1) * 16;
        unsigned oo[8];
#pragma unroll
        for (int j = 0; j < 8; ++j)
            oo[j] = (unsigned)Ls[t16 + 2 * j][dr] | ((unsigned)Ls[t16 + 2 * j + 1][dr] << 16);
        unsigned short* dst = Vt + ((size_t)bh * DH + dr) * TT + t0 + t16;
        *(uint4*)(dst)     = make_uint4(oo[0], oo[1], oo[2], oo[3]);
        *(uint4*)(dst + 8) = make_uint4(oo[4], oo[5], oo[6], oo[7]);
    }
}

// ---------------------------------------------------------------------------
// Flash attention R19 = R17 swapped-QK^T register-softmax, with:
//  - Lbc LDS broadcast replaced by __shfl(val, qr) lane reads (ds_bpermute;
//    lanes l and l^32 hold identical per-query state, qr<32 always)
//    -> LDS exactly 32768 B -> 5 blocks/CU (was 4), 10 waves/CU (+25% TLP)
//  - P pack via v_cvt_pkrtz (1 instr vs cvt+cvt+or); RTZ on P only, <=1ulp
// Block: 128 thr (2 waves), 32 queries/wave. Grid 1024. No P LDS buffer;
// bank conflicts measured 0 in R17.
// ---------------------------------------------------------------------------
__global__ __launch_bounds__(128, 2)
void attn_mfma(const unsigned short* __restrict__ Qb, const unsigned short* __restrict__ Kb,
               const unsigned short* __restrict__ Vt, unsigned short* __restrict__ Yb) {
    __shared__ __align__(16) unsigned short Ks[2][32 * 128];   // [key][dh] swizzled
    __shared__ __align__(16) unsigned short Vs[2][128 * 32];   // [dh][key] swizzled

    const int tid  = threadIdx.x;
    const int lane = tid & 63, wid = tid >> 6;   // wid 0..1
    const int l31 = lane & 31, g2 = lane >> 5;
    const int q0 = blockIdx.x * 64;
    const int bh = blockIdx.y;
    const int b = bh >> 4, h = bh & 15, hk = h >> 2;

    const size_t kbase = (size_t)(b * TT) * KVC + hk * DH;
    const size_t vbase = (size_t)(b * HKV_ + hk) * DH * TT;

    // stage one 32-key K/V tile (8 gll16 per thread, 128 thr)
#define STAGE(buf, st)                                                         \
    do {                                                                       \
        _Pragma("unroll")                                                      \
        for (int r = 0; r < 4; ++r) {                                          \
            const int qq = r * 128 + tid;                                      \
            const int key = qq >> 4, c = qq & 15;                              \
            const int sc = c ^ (key & 7) ^ (((key >> 3) & 1) << 3);            \
            gll16(Kb + kbase + (size_t)((st) + key) * KVC + sc * 8,            \
                  &Ks[buf][qq * 8]);                                           \
        }                                                                      \
        _Pragma("unroll")                                                      \
        for (int r = 0; r < 4; ++r) {                                          \
            const int qq = r * 128 + tid;                                      \
            const int d = qq >> 2, c = qq & 3;                                 \
            const int sc = c ^ (d & 3) ^ ((d >> 2) & 3);                       \
            gll16(Vt + vbase + (size_t)d * TT + (st) + sc * 8,                 \
                  &Vs[buf][qq * 8]);                                           \
        }                                                                      \
    } while (0)

    STAGE(0, 0);   // tile 0 in flight while we load/norm Q

    // ---- Q fragments: query = l31 (B-operand col); lane holds 64 of 128
    // dims: dh = s*16 + g2*8 + j for s=0..7 ----
    f16x8 qf[8];
    {
        const unsigned short* qp =
            Qb + (size_t)(b * TT + q0 + wid * 32 + l31) * QVN + h * DH + g2 * 8;
#pragma unroll
        for (int s = 0; s < 8; ++s) qf[s] = *(const f16x8*)(qp + s * 16);
    }
    // fused rmsnorm * log2e (pair lane holds the other 64 dims)
    {
        float ss = 0.f;
#pragma unroll
        for (int s = 0; s < 8; ++s)
#pragma unroll
            for (int j = 0; j < 8; ++j) { const float v = (float)qf[s][j]; ss += v * v; }
        ss += __shfl_xor(ss, 32);
        const float qsc = rsqrtf(ss * (1.f / DH) + 1.1920929e-07f) * 1.4426950408889634f;
#pragma unroll
        for (int s = 0; s < 8; ++s)
#pragma unroll
            for (int j = 0; j < 8; ++j)
                qf[s][j] = (_Float16)((float)qf[s][j] * qsc);
    }

    float mr = -3.0e38f, lr = 0.f;   // per-query state (query = l31)
    f32x16 accO[4] = {};             // O[query(reg)][dh = db*32 + l31]

    asm volatile("s_waitcnt vmcnt(0)" ::: "memory");
    __builtin_amdgcn_s_barrier();

    const int NT = TT / 32;   // 64 tiles
    for (int t = 0; t < NT; ++t) {
        const int cur = t & 1;
        if (t + 1 < NT) STAGE(cur ^ 1, (t + 1) * 32);   // depth-1 prefetch

        const unsigned short* ksp = Ks[cur];
        const unsigned short* vsp = Vs[cur];

        // ---- S^T = K Q : D[key][query], query = l31 lane-local ----
        f32x16 sA = {};
        __builtin_amdgcn_s_setprio(1);
#pragma unroll
        for (int s = 0; s < 8; ++s) {
            const int kch = (2 * s + g2) ^ (l31 & 7) ^ (((l31 >> 3) & 1) << 3);
            const f16x8 kf = *(const f16x8*)&ksp[l31 * 128 + kch * 8];
            sA = __builtin_amdgcn_mfma_f32_32x32x16_f16(kf, qf[s], sA, 0, 0, 0);
        }
        __builtin_amdgcn_s_setprio(0);

        // ---- register softmax for query l31 (16 own keys + 16 in pair) ----
        float m0 = sA[0];
#pragma unroll
        for (int r = 1; r < 16; ++r) m0 = fmaxf(m0, sA[r]);
        const float pairm = fmaxf(m0, __shfl_xor(m0, 32));
        const bool need = pairm > mr + 8.f;
        if (__any(need)) {                      // rare: defer-max THR=8
            const float mn = fmaxf(mr, pairm);
            const float sc = __builtin_amdgcn_exp2f(mr - mn);
            mr = mn;
            lr *= sc;
#pragma unroll
            for (int r = 0; r < 16; ++r) {
                const int qr = (r & 3) + 8 * (r >> 2) + 4 * g2;
                const float scr = __shfl(sc, qr);   // lane qr holds query qr
                accO[0][r] *= scr; accO[1][r] *= scr;
                accO[2][r] *= scr; accO[3][r] *= scr;
            }
        }

        float p[16];
        float s16 = 0.f;
#pragma unroll
        for (int r = 0; r < 16; ++r) {
            p[r] = __builtin_amdgcn_exp2f(sA[r] - mr);
            s16 += p[r];
        }
        lr += s16 + __shfl_xor(s16, 32);

        // ---- PV: A = P (row=query=l31, k=keys), B = V (col=dh, k=keys) ----
        __builtin_amdgcn_s_setprio(1);
#pragma unroll
        for (int ks = 0; ks < 2; ++ks) {
            const unsigned w0 = pkrtz(p[8 * ks + 0], p[8 * ks + 1]);
            const unsigned w1 = pkrtz(p[8 * ks + 2], p[8 * ks + 3]);
            const unsigned w2 = pkrtz(p[8 * ks + 4], p[8 * ks + 5]);
            const unsigned w3 = pkrtz(p[8 * ks + 6], p[8 * ks + 7]);
            const unsigned sw0 = __shfl_xor(w0, 32);
            const unsigned sw1 = __shfl_xor(w1, 32);
            const unsigned sw2 = __shfl_xor(w2, 32);
            const unsigned sw3 = __shfl_xor(w3, 32);
            // g2=0 frag keys 16ks+0..7; g2=1 frag keys 16ks+8..15
            const uint4 uw = (g2 == 0) ? make_uint4(w0, w1, sw0, sw1)
                                       : make_uint4(sw2, sw3, w2, w3);
            const f16x8 pa = __builtin_bit_cast(f16x8, uw);
#pragma unroll
            for (int db = 0; db < 4; ++db) {
                const int dr = db * 32 + l31;
                const int vch = (2 * ks + g2) ^ (dr & 3) ^ ((dr >> 2) & 3);
                const f16x8 vf = *(const f16x8*)&vsp[dr * 32 + vch * 8];
                accO[db] = __builtin_amdgcn_mfma_f32_32x32x16_f16(pa, vf, accO[db], 0, 0, 0);
            }
        }
        __builtin_amdgcn_s_setprio(0);

        asm volatile("s_waitcnt vmcnt(0)" ::: "memory");
        __builtin_amdgcn_s_barrier();
    }
#undef STAGE

    // ---- finalize: per-query 1/l via lane shfl, divide, store ----
    const float invl = 1.f / lr;                // per-lane (query l31)
#pragma unroll
    for (int r = 0; r < 16; ++r) {
        const int qr = (r & 3) + 8 * (r >> 2) + 4 * g2;
        const float inv = __shfl(invl, qr);
        const int trow = q0 + wid * 32 + qr;
#pragma unroll
        for (int db = 0; db < 4; ++db) {
            const int col = h * DH + db * 32 + l31;
            Yb[(size_t)(b * TT + trow) * CC + col] = f2h(accO[db][r] * inv);
        }
    }
}

// ---------------------------------------------------------------------------
// RMSNorm rows of 2048, fp16 in -> fp32 out (final output norm)
// ---------------------------------------------------------------------------
__global__ __launch_bounds__(256)
void rms2048_h(const unsigned short* __restrict__ in, float* __restrict__ out) {
    __shared__ float red[4];
    const int tid = threadIdx.x;
    const unsigned short* p = in + (size_t)blockIdx.x * CC + tid * 8;
    const uint4 u = *(const uint4*)p;
    float v[8];
    v[0] = h2f((unsigned short)(u.x & 0xffff)); v[1] = h2f((unsigned short)(u.x >> 16));
    v[2] = h2f((unsigned short)(u.y & 0xffff)); v[3] = h2f((unsigned short)(u.y >> 16));
    v[4] = h2f((unsigned short)(u.z & 0xffff)); v[5] = h2f((unsigned short)(u.z >> 16));
    v[6] = h2f((unsigned short)(u.w & 0xffff)); v[7] = h2f((unsigned short)(u.w >> 16));
    float ss = 0.f;
#pragma unroll
    for (int j = 0; j < 8; ++j) ss += v[j] * v[j];
#pragma unroll
    for (int o = 32; o >= 1; o >>= 1) ss += __shfl_xor(ss, o);
    if ((tid & 63) == 0) red[tid >> 6] = ss;
    __syncthreads();
    const float tot = red[0] + red[1] + red[2] + red[3];
    const float sc = rsqrtf(tot * (1.f / CC) + 1.1920929e-07f);
    float* q = out + (size_t)blockIdx.x * CC + tid * 8;
    *(float4*)&q[0] = make_float4(v[0] * sc, v[1] * sc, v[2] * sc, v[3] * sc);
    *(float4*)&q[4] = make_float4(v[4] * sc, v[5] * sc, v[6] * sc, v[7] * sc);
}

// ---------------------------------------------------------------------------
extern "C" void kernel_launch(void* const* d_in, const int* in_sizes, int n_in,
                              void* d_out, int out_size, void* d_ws, size_t ws_size,
                              hipStream_t stream) {
    const float* x  = (const float*)d_in[0];
    const float* Wq = (const float*)d_in[1];
    // d_in[2] = Wk — unused by the reference (K = rmsnorm(V))
    const float* Wv = (const float*)d_in[3];
    const float* Wo = (const float*)d_in[4];
    float* out = (float*)d_out;

    char* ws = (char*)d_ws;
    const size_t MB = 1024 * 1024;
    unsigned short* xb   = (unsigned short*)(ws);            // 16 MB (x cast; later fp16 O)
    unsigned short* WqvT = (unsigned short*)(ws + 16 * MB);  // 10 MB ([2560][2048])
    unsigned short* QVg  = (unsigned short*)(ws + 26 * MB);  // 20 MB ([4096][2560])
    unsigned short* Kb   = (unsigned short*)(ws + 46 * MB);  //  4 MB
    unsigned short* Vt   = (unsigned short*)(ws + 50 * MB);  //  4 MB
    unsigned short* Yb   = (unsigned short*)(ws + 54 * MB);  // 16 MB
    unsigned short* WoT  = (unsigned short*)(ws + 70 * MB);  //  8 MB (peak 78 MB)

    const unsigned short* Qb = QVg;          // Q cols 0..2047, row stride QVN
    const unsigned short* Vg = QVg + CC;     // V cols 2048..2559, row stride QVN

    const dim3 blk(256);

    prep<<<11264, blk, 0, stream>>>(x, xb, Wq, Wv, Wo, WqvT, WoT);

    gemm_bt<1><<<dim3(QVN / 128, MM / 128), blk, 0, stream>>>(xb, WqvT, QVg, MM, QVN, CC);

    kvprep<<<dim3(TT / 32, BB * HKV_), blk, 0, stream>>>(Vg, Kb, Vt);

    attn_mfma<<<dim3(TT / 64, BB * HQ_), dim3(128), 0, stream>>>(Qb, Kb, Vt, Yb);

    gemm_bt<1><<<dim3(CC / 128, MM / 128), blk, 0, stream>>>(Yb, WoT, xb, MM, CC, CC);
    rms2048_h<<<MM, blk, 0, stream>>>(xb, out);
}

// Round 20
// 243.195 us; speedup vs baseline: 1.0133x; 1.0133x over previous
//
#include <hip/hip_runtime.h>
#include <math.h>

// Problem constants (B=2, T=2048, C=2048, HQ=16, HKV=4, Dh=128, WIN=256)
#define BB   2
#define TT   2048
#define CC   2048
#define HQ_  16
#define HKV_ 4
#define DH   128
#define MM   (BB * TT)          // 4096 rows
#define KVC  (HKV_ * DH)        // 512
#define QVN  (CC + KVC)         // 2560: fused Q|V projection width

typedef __attribute__((ext_vector_type(8)))  _Float16 f16x8;
typedef __attribute__((ext_vector_type(4)))  float    f32x4;
typedef __attribute__((ext_vector_type(16))) float    f32x16;

__device__ __forceinline__ unsigned short f2h(float x) {
    _Float16 h = (_Float16)x;                 // RNE v_cvt_f16_f32
    return __builtin_bit_cast(unsigned short, h);
}
__device__ __forceinline__ float h2f(unsigned short u) {
    return (float)__builtin_bit_cast(_Float16, u);
}
__device__ __forceinline__ unsigned pk2(float a, float b) {
    return (unsigned)f2h(a) | ((unsigned)f2h(b) << 16);
}
__device__ __forceinline__ void gll16(const void* g, void* l) {
    __builtin_amdgcn_global_load_lds(
        (const __attribute__((address_space(1))) unsigned int*)g,
        (__attribute__((address_space(3))) unsigned int*)l, 16, 0, 0);
}
// bijective XCD-aware tile remap (T1, m204 form).
__device__ __forceinline__ int xcd_swizzle(int lid, int nwg) {
    const int xcd = lid & 7, rank = lid >> 3;
    const int q8 = nwg >> 3, r8 = nwg & 7;
    return (xcd < r8 ? xcd * (q8 + 1) : r8 * (q8 + 1) + (xcd - r8) * q8) + rank;
}

// ---------------------------------------------------------------------------
// prep: ONE dispatch = fp32->fp16 cast of x (+) transpose-casts of Wq,Wv,Wo.
// ---------------------------------------------------------------------------
__device__ __forceinline__ void tcast_tile(const float* __restrict__ W,
                                           unsigned short* __restrict__ WT,
                                           int Kd, int Nd, int n0, int k0,
                                           float Ls[32][33]) {
    const int i = threadIdx.x;
    {
        const int kr = i >> 3, n4 = (i & 7) * 4;
        float4 v = *(const float4*)&W[(size_t)(k0 + kr) * Nd + n0 + n4];
        Ls[kr][n4 + 0] = v.x; Ls[kr][n4 + 1] = v.y;
        Ls[kr][n4 + 2] = v.z; Ls[kr][n4 + 3] = v.w;
    }
    __syncthreads();
    {
        const int nr = i >> 3, k4 = (i & 7) * 4;
        uint2 o;
        o.x = pk2(Ls[k4 + 0][nr], Ls[k4 + 1][nr]);
        o.y = pk2(Ls[k4 + 2][nr], Ls[k4 + 3][nr]);
        *(uint2*)&WT[(size_t)(n0 + nr) * Kd + k0 + k4] = o;
    }
}

__global__ __launch_bounds__(256)
void prep(const float* __restrict__ x,  unsigned short* __restrict__ xb,
          const float* __restrict__ Wq, const float* __restrict__ Wv,
          const float* __restrict__ Wo, unsigned short* __restrict__ WqvT,
          unsigned short* __restrict__ WoT) {
    __shared__ float Ls[32][33];
    const int bid = blockIdx.x;
    if (bid < 2048) {
        const int n8 = MM * CC / 8;
        int i = bid * 256 + threadIdx.x;
        for (; i < n8; i += 2048 * 256) {
            const float4 a = ((const float4*)x)[i * 2 + 0];
            const float4 b = ((const float4*)x)[i * 2 + 1];
            uint4 o;
            o.x = pk2(a.x, a.y); o.y = pk2(a.z, a.w);
            o.z = pk2(b.x, b.y); o.w = pk2(b.z, b.w);
            ((uint4*)xb)[i] = o;
        }
    } else if (bid < 2048 + 4096) {
        const int t = bid - 2048;
        tcast_tile(Wq, WqvT, CC, CC, (t & 63) * 32, (t >> 6) * 32, Ls);
    } else if (bid < 2048 + 4096 + 1024) {
        const int t = bid - (2048 + 4096);
        tcast_tile(Wv, WqvT + (size_t)CC * CC, CC, KVC, (t & 15) * 32, (t >> 4) * 32, Ls);
    } else {
        const int t = bid - (2048 + 4096 + 1024);
        tcast_tile(Wo, WoT, CC, CC, (t & 63) * 32, (t >> 6) * 32, Ls);
    }
}

// ---------------------------------------------------------------------------
// fp16 MFMA GEMM, B^T input (m97 structure + T1 swizzle). Unchanged.
// ---------------------------------------------------------------------------
template<int F16OUT>
__global__ __launch_bounds__(256)
void gemm_bt(const unsigned short* __restrict__ A, const unsigned short* __restrict__ Bt,
             void* __restrict__ Cout, int M, int N, int K) {
    __shared__ __align__(16) unsigned short As[128 * 64];
    __shared__ __align__(16) unsigned short Bs[128 * 64];
    const int tid  = threadIdx.x;
    const int lane = tid & 63, wid = tid >> 6;
    const int g = lane >> 4, l15 = lane & 15;
    const int nwg  = gridDim.x * gridDim.y;
    const int tile = xcd_swizzle(blockIdx.y * gridDim.x + blockIdx.x, nwg);
    const int bm = (tile / gridDim.x) * 128, bn = (tile % gridDim.x) * 128;
    const int wr = (wid >> 1) * 64, wc = (wid & 1) * 64;

    f32x4 acc[4][4] = {};

    for (int kt = 0; kt < K; kt += 64) {
        __syncthreads();
#pragma unroll
        for (int r = 0; r < 4; ++r) {
            const int q = r * 256 + tid;
            const int row = q >> 3, c = q & 7, sc = c ^ (row & 7);
            gll16(A + (size_t)(bm + row) * K + kt + sc * 8, As + q * 8);
        }
#pragma unroll
        for (int r = 0; r < 4; ++r) {
            const int q = r * 256 + tid;
            const int row = q >> 3, c = q & 7, sc = c ^ (row & 7);
            gll16(Bt + (size_t)(bn + row) * K + kt + sc * 8, Bs + q * 8);
        }
        __syncthreads();

#pragma unroll
        for (int kk = 0; kk < 2; ++kk) {
            f16x8 af[4], bfr[4];
#pragma unroll
            for (int m = 0; m < 4; ++m) {
                const int row = wr + m * 16 + l15;
                const int ch = (kk * 4 + g) ^ (row & 7);
                af[m] = *(const f16x8*)&As[row * 64 + ch * 8];
            }
#pragma unroll
            for (int n = 0; n < 4; ++n) {
                const int row = wc + n * 16 + l15;
                const int ch = (kk * 4 + g) ^ (row & 7);
                bfr[n] = *(const f16x8*)&Bs[row * 64 + ch * 8];
            }
#pragma unroll
            for (int m = 0; m < 4; ++m)
#pragma unroll
                for (int n = 0; n < 4; ++n)
                    acc[m][n] = __builtin_amdgcn_mfma_f32_16x16x32_f16(
                        af[m], bfr[n], acc[m][n], 0, 0, 0);
        }
    }

#pragma unroll
    for (int m = 0; m < 4; ++m)
#pragma unroll
        for (int n = 0; n < 4; ++n)
#pragma unroll
            for (int r = 0; r < 4; ++r) {
                const int row = bm + wr + m * 16 + g * 4 + r;
                const int col = bn + wc + n * 16 + l15;
                const float v = acc[m][n][r];
                if (F16OUT)
                    ((unsigned short*)Cout)[(size_t)row * N + col] = f2h(v);
                else
                    ((float*)Cout)[(size_t)row * N + col] = v;
            }
}

// ---------------------------------------------------------------------------
// kvprep: fused K=rmsnorm(V) + Vt transpose build. Unchanged.
// ---------------------------------------------------------------------------
__global__ __launch_bounds__(256)
void kvprep(const unsigned short* __restrict__ Vg,
            unsigned short* __restrict__ Kb, unsigned short* __restrict__ Vt) {
    __shared__ unsigned short Ls[32][132];
    const int t0 = blockIdx.x * 32;
    const int bh = blockIdx.y;
    const int b = bh >> 2, hk = bh & 3;
    const int tid = threadIdx.x;

    const int tr = tid >> 3, c16 = (tid & 7) * 16;
    const unsigned short* src =
        Vg + (size_t)(b * TT + t0 + tr) * QVN + hk * DH + c16;
    const uint4 u0 = *(const uint4*)(src);
    const uint4 u1 = *(const uint4*)(src + 8);
    *(uint4*)&Ls[tr][c16]     = u0;
    *(uint4*)&Ls[tr][c16 + 8] = u1;

    float v[16];
    {
        const unsigned uu[8] = {u0.x, u0.y, u0.z, u0.w, u1.x, u1.y, u1.z, u1.w};
#pragma unroll
        for (int j = 0; j < 8; ++j) {
            v[2 * j]     = h2f((unsigned short)(uu[j] & 0xffff));
            v[2 * j + 1] = h2f((unsigned short)(uu[j] >> 16));
        }
    }
    float ss = 0.f;
#pragma unroll
    for (int j = 0; j < 16; ++j) ss += v[j] * v[j];
    ss += __shfl_xor(ss, 1);
    ss += __shfl_xor(ss, 2);
    ss += __shfl_xor(ss, 4);
    const float sc = rsqrtf(ss * (1.f / DH) + 1.1920929e-07f);

    {
        unsigned short* kd = Kb + (size_t)(b * TT + t0 + tr) * KVC + hk * DH + c16;
        unsigned oo[8];
#pragma unroll
        for (int j = 0; j < 8; ++j)
            oo[j] = pk2(v[2 * j] * sc, v[2 * j + 1] * sc);
        *(uint4*)(kd)     = make_uint4(oo[0], oo[1], oo[2], oo[3]);
        *(uint4*)(kd + 8) = make_uint4(oo[4], oo[5], oo[6], oo[7]);
    }
    __syncthreads();

    {
        const int dr = tid >> 1, t16 = (tid & 1) * 16;
        unsigned oo[8];
#pragma unroll
        for (int j = 0; j < 8; ++j)
            oo[j] = (unsigned)Ls[t16 + 2 * j][dr] | ((unsigned)Ls[t16 + 2 * j + 1][dr] << 16);
        unsigned short* dst = Vt + ((size_t)bh * DH + dr) * TT + t0 + t16;
        *(uint4*)(dst)     = make_uint4(oo[0], oo[1], oo[2], oo[3]);
        *(uint4*)(dst + 8) = make_uint4(oo[4], oo[5], oo[6], oo[7]);
    }
}

// ---------------------------------------------------------------------------
// Flash attention (R20 = exact R17 config -- best measured: 117 us, total
// 244.4 us, MfmaUtil 25%, bank conflicts 0).
// Swapped-QK^T 32x32x16 register-softmax. Block: 128 thr (2 waves), 32
// queries/wave -> 64 q-rows/block; grid 1024 (4 blocks/CU). LDS 32.5KB:
// dbuf K[32][128]+Vt[128][32], NO P buffer. S = mfma(K,Q): D col=lane&31=
// QUERY (lane-local softmax); P->PV A-frag via 4 pack + 4 shfl_xor(32) per
// k-step. O rescale / final div via 256B wave-private Lbc broadcast.
// (R19 verdict: dropping Lbc for shfl + 32KB LDS did NOT gain occupancy
// and cost VGPR/VALU -- this config is the measured optimum.)
// ---------------------------------------------------------------------------
__global__ __launch_bounds__(128, 2)
void attn_mfma(const unsigned short* __restrict__ Qb, const unsigned short* __restrict__ Kb,
               const unsigned short* __restrict__ Vt, unsigned short* __restrict__ Yb) {
    __shared__ __align__(16) unsigned short Ks[2][32 * 128];   // [key][dh] swizzled
    __shared__ __align__(16) unsigned short Vs[2][128 * 32];   // [dh][key] swizzled
    __shared__ float Lbc[2][32];                               // per-wave broadcast

    const int tid  = threadIdx.x;
    const int lane = tid & 63, wid = tid >> 6;   // wid 0..1
    const int l31 = lane & 31, g2 = lane >> 5;
    const int q0 = blockIdx.x * 64;
    const int bh = blockIdx.y;
    const int b = bh >> 4, h = bh & 15, hk = h >> 2;

    const size_t kbase = (size_t)(b * TT) * KVC + hk * DH;
    const size_t vbase = (size_t)(b * HKV_ + hk) * DH * TT;

    // stage one 32-key K/V tile (8 gll16 per thread, 128 thr)
#define STAGE(buf, st)                                                         \
    do {                                                                       \
        _Pragma("unroll")                                                      \
        for (int r = 0; r < 4; ++r) {                                          \
            const int qq = r * 128 + tid;                                      \
            const int key = qq >> 4, c = qq & 15;                              \
            const int sc = c ^ (key & 7) ^ (((key >> 3) & 1) << 3);            \
            gll16(Kb + kbase + (size_t)((st) + key) * KVC + sc * 8,            \
                  &Ks[buf][qq * 8]);                                           \
        }                                                                      \
        _Pragma("unroll")                                                      \
        for (int r = 0; r < 4; ++r) {                                          \
            const int qq = r * 128 + tid;                                      \
            const int d = qq >> 2, c = qq & 3;                                 \
            const int sc = c ^ (d & 3) ^ ((d >> 2) & 3);                       \
            gll16(Vt + vbase + (size_t)d * TT + (st) + sc * 8,                 \
                  &Vs[buf][qq * 8]);                                           \
        }                                                                      \
    } while (0)

    STAGE(0, 0);   // tile 0 in flight while we load/norm Q

    // ---- Q fragments: query = l31 (B-operand col); lane holds 64 of 128
    // dims: dh = s*16 + g2*8 + j for s=0..7 ----
    f16x8 qf[8];
    {
        const unsigned short* qp =
            Qb + (size_t)(b * TT + q0 + wid * 32 + l31) * QVN + h * DH + g2 * 8;
#pragma unroll
        for (int s = 0; s < 8; ++s) qf[s] = *(const f16x8*)(qp + s * 16);
    }
    // fused rmsnorm * log2e (pair lane holds the other 64 dims)
    {
        float ss = 0.f;
#pragma unroll
        for (int s = 0; s < 8; ++s)
#pragma unroll
            for (int j = 0; j < 8; ++j) { const float v = (float)qf[s][j]; ss += v * v; }
        ss += __shfl_xor(ss, 32);
        const float qsc = rsqrtf(ss * (1.f / DH) + 1.1920929e-07f) * 1.4426950408889634f;
#pragma unroll
        for (int s = 0; s < 8; ++s)
#pragma unroll
            for (int j = 0; j < 8; ++j)
                qf[s][j] = (_Float16)((float)qf[s][j] * qsc);
    }

    float mr = -3.0e38f, lr = 0.f;   // per-query state (query = l31)
    f32x16 accO[4] = {};             // O[query(reg)][dh = db*32 + l31]

    asm volatile("s_waitcnt vmcnt(0)" ::: "memory");
    __builtin_amdgcn_s_barrier();

    const int NT = TT / 32;   // 64 tiles
    for (int t = 0; t < NT; ++t) {
        const int cur = t & 1;
        if (t + 1 < NT) STAGE(cur ^ 1, (t + 1) * 32);   // depth-1 prefetch

        const unsigned short* ksp = Ks[cur];
        const unsigned short* vsp = Vs[cur];

        // ---- S^T = K Q : D[key][query], query = l31 lane-local ----
        f32x16 sA = {};
        __builtin_amdgcn_s_setprio(1);
#pragma unroll
        for (int s = 0; s < 8; ++s) {
            const int kch = (2 * s + g2) ^ (l31 & 7) ^ (((l31 >> 3) & 1) << 3);
            const f16x8 kf = *(const f16x8*)&ksp[l31 * 128 + kch * 8];
            sA = __builtin_amdgcn_mfma_f32_32x32x16_f16(kf, qf[s], sA, 0, 0, 0);
        }
        __builtin_amdgcn_s_setprio(0);

        // ---- register softmax for query l31 (16 own keys + 16 in pair) ----
        float m0 = sA[0];
#pragma unroll
        for (int r = 1; r < 16; ++r) m0 = fmaxf(m0, sA[r]);
        const float pairm = fmaxf(m0, __shfl_xor(m0, 32));
        const bool need = pairm > mr + 8.f;
        if (__any(need)) {                      // rare: defer-max THR=8
            const float mn = fmaxf(mr, pairm);
            const float sc = __builtin_amdgcn_exp2f(mr - mn);
            mr = mn;
            lr *= sc;
            Lbc[wid][l31] = sc;                 // pair lane writes same value
#pragma unroll
            for (int r = 0; r < 16; ++r) {
                const int qr = (r & 3) + 8 * (r >> 2) + 4 * g2;
                const float scr = Lbc[wid][qr];
                accO[0][r] *= scr; accO[1][r] *= scr;
                accO[2][r] *= scr; accO[3][r] *= scr;
            }
        }

        float p[16];
        float s16 = 0.f;
#pragma unroll
        for (int r = 0; r < 16; ++r) {
            p[r] = __builtin_amdgcn_exp2f(sA[r] - mr);
            s16 += p[r];
        }
        lr += s16 + __shfl_xor(s16, 32);

        // ---- PV: A = P (row=query=l31, k=keys), B = V (col=dh, k=keys) ----
        __builtin_amdgcn_s_setprio(1);
#pragma unroll
        for (int ks = 0; ks < 2; ++ks) {
            // own words: keys {16ks+4g2, +1}, {+2,+3}, {16ks+8+4g2,+1}, {+2,+3}
            const unsigned w0 = pk2(p[8 * ks + 0], p[8 * ks + 1]);
            const unsigned w1 = pk2(p[8 * ks + 2], p[8 * ks + 3]);
            const unsigned w2 = pk2(p[8 * ks + 4], p[8 * ks + 5]);
            const unsigned w3 = pk2(p[8 * ks + 6], p[8 * ks + 7]);
            const unsigned sw0 = __shfl_xor(w0, 32);
            const unsigned sw1 = __shfl_xor(w1, 32);
            const unsigned sw2 = __shfl_xor(w2, 32);
            const unsigned sw3 = __shfl_xor(w3, 32);
            // g2=0 frag keys 16ks+0..7; g2=1 frag keys 16ks+8..15
            const uint4 uw = (g2 == 0) ? make_uint4(w0, w1, sw0, sw1)
                                       : make_uint4(sw2, sw3, w2, w3);
            const f16x8 pa = __builtin_bit_cast(f16x8, uw);
#pragma unroll
            for (int db = 0; db < 4; ++db) {
                const int dr = db * 32 + l31;
                const int vch = (2 * ks + g2) ^ (dr & 3) ^ ((dr >> 2) & 3);
                const f16x8 vf = *(const f16x8*)&vsp[dr * 32 + vch * 8];
                accO[db] = __builtin_amdgcn_mfma_f32_32x32x16_f16(pa, vf, accO[db], 0, 0, 0);
            }
        }
        __builtin_amdgcn_s_setprio(0);

        asm volatile("s_waitcnt vmcnt(0)" ::: "memory");
        __builtin_amdgcn_s_barrier();
    }
#undef STAGE

    // ---- finalize: broadcast 1/l per query, divide, store ----
    Lbc[wid][l31] = 1.f / lr;                   // pair lane writes same value
#pragma unroll
    for (int r = 0; r < 16; ++r) {
        const int qr = (r & 3) + 8 * (r >> 2) + 4 * g2;
        const float inv = Lbc[wid][qr];
        const int trow = q0 + wid * 32 + qr;
#pragma unroll
        for (int db = 0; db < 4; ++db) {
            const int col = h * DH + db * 32 + l31;
            Yb[(size_t)(b * TT + trow) * CC + col] = f2h(accO[db][r] * inv);
        }
    }
}

// ---------------------------------------------------------------------------
// RMSNorm rows of 2048, fp16 in -> fp32 out (final output norm)
// ---------------------------------------------------------------------------
__global__ __launch_bounds__(256)
void rms2048_h(const unsigned short* __restrict__ in, float* __restrict__ out) {
    __shared__ float red[4];
    const int tid = threadIdx.x;
    const unsigned short* p = in + (size_t)blockIdx.x * CC + tid * 8;
    const uint4 u = *(const uint4*)p;
    float v[8];
    v[0] = h2f((unsigned short)(u.x & 0xffff)); v[1] = h2f((unsigned short)(u.x >> 16));
    v[2] = h2f((unsigned short)(u.y & 0xffff)); v[3] = h2f((unsigned short)(u.y >> 16));
    v[4] = h2f((unsigned short)(u.z & 0xffff)); v[5] = h2f((unsigned short)(u.z >> 16));
    v[6] = h2f((unsigned short)(u.w & 0xffff)); v[7] = h2f((unsigned short)(u.w >> 16));
    float ss = 0.f;
#pragma unroll
    for (int j = 0; j < 8; ++j) ss += v[j] * v[j];
#pragma unroll
    for (int o = 32; o >= 1; o >>= 1) ss += __shfl_xor(ss, o);
    if ((tid & 63) == 0) red[tid >> 6] = ss;
    __syncthreads();
    const float tot = red[0] + red[1] + red[2] + red[3];
    const float sc = rsqrtf(tot * (1.f / CC) + 1.1920929e-07f);
    float* q = out + (size_t)blockIdx.x * CC + tid * 8;
    *(float4*)&q[0] = make_float4(v[0] * sc, v[1] * sc, v[2] * sc, v[3] * sc);
    *(float4*)&q[4] = make_float4(v[4] * sc, v[5] * sc, v[6] * sc, v[7] * sc);
}

// ---------------------------------------------------------------------------
extern "C" void kernel_launch(void* const* d_in, const int* in_sizes, int n_in,
                              void* d_out, int out_size, void* d_ws, size_t ws_size,
                              hipStream_t stream) {
    const float* x  = (const float*)d_in[0];
    const float* Wq = (const float*)d_in[1];
    // d_in[2] = Wk — unused by the reference (K = rmsnorm(V))
    const float* Wv = (const float*)d_in[3];
    const float* Wo = (const float*)d_in[4];
    float* out = (float*)d_out;

    char* ws = (char*)d_ws;
    const size_t MB = 1024 * 1024;
    unsigned short* xb   = (unsigned short*)(ws);            // 16 MB (x cast; later fp16 O)
    unsigned short* WqvT = (unsigned short*)(ws + 16 * MB);  // 10 MB ([2560][2048])
    unsigned short* QVg  = (unsigned short*)(ws + 26 * MB);  // 20 MB ([4096][2560])
    unsigned short* Kb   = (unsigned short*)(ws + 46 * MB);  //  4 MB
    unsigned short* Vt   = (unsigned short*)(ws + 50 * MB);  //  4 MB
    unsigned short* Yb   = (unsigned short*)(ws + 54 * MB);  // 16 MB
    unsigned short* WoT  = (unsigned short*)(ws + 70 * MB);  //  8 MB (peak 78 MB)

    const unsigned short* Qb = QVg;          // Q cols 0..2047, row stride QVN
    const unsigned short* Vg = QVg + CC;     // V cols 2048..2559, row stride QVN

    const dim3 blk(256);

    prep<<<11264, blk, 0, stream>>>(x, xb, Wq, Wv, Wo, WqvT, WoT);

    gemm_bt<1><<<dim3(QVN / 128, MM / 128), blk, 0, stream>>>(xb, WqvT, QVg, MM, QVN, CC);

    kvprep<<<dim3(TT / 32, BB * HKV_), blk, 0, stream>>>(Vg, Kb, Vt);

    attn_mfma<<<dim3(TT / 64, BB * HQ_), dim3(128), 0, stream>>>(Qb, Kb, Vt, Yb);

    gemm_bt<1><<<dim3(CC / 128, MM / 128), blk, 0, stream>>>(Yb, WoT, xb, MM, CC, CC);
    rms2048_h<<<MM, blk, 0, stream>>>(xb, out);
}